// Round 15
// baseline (141.536 us; speedup 1.0000x reference)
//
#include <hip/hip_runtime.h>

#define AS1 __attribute__((address_space(1)))
#define AS3 __attribute__((address_space(3)))

typedef __bf16 bf16x8 __attribute__((ext_vector_type(8)));
typedef float f32x4 __attribute__((ext_vector_type(4)));
typedef unsigned short ushort8 __attribute__((ext_vector_type(8)));

// round-to-nearest-even f32 -> bf16 (prep only; hot path uses native casts)
__device__ __forceinline__ unsigned short f2bf(float f) {
  union { float f; unsigned u; } v; v.f = f;
  unsigned u = v.u;
  unsigned r = (u + 0x7fffu + ((u >> 16) & 1u)) >> 16;
  return (unsigned short)r;
}

// ---------------------------------------------------------------------------
// prep: fused dcalc_a + wconv (r9-verified). Grid (4,32), block 256.
// ---------------------------------------------------------------------------
__global__ __launch_bounds__(256) void prep_kernel(const float* __restrict__ y,
                                                   const float* __restrict__ W,
                                                   float* __restrict__ partial,
                                                   unsigned short* __restrict__ WT) {
  __shared__ float ysq[32][32];  // [i_local][b]
  const int o = blockIdx.x * 256 + threadIdx.x;
  const int i0 = blockIdx.y * 32;
  for (int e = threadIdx.x; e < 1024; e += 256) {
    int il = e >> 5, b = e & 31;
    float t = y[b * 1024 + i0 + il] * 0.03125f;
    ysq[il][b] = t * t;
  }
  __syncthreads();

  f32x4 acc[8] = {};
  ushort8 wb[4];
#pragma unroll
  for (int il = 0; il < 32; ++il) {
    float w = W[(size_t)(i0 + il) * 1024 + o];
    wb[il >> 3][il & 7] = f2bf(w);
    float w2 = w * w;
#pragma unroll
    for (int b4 = 0; b4 < 8; ++b4) {
      f32x4 q = *(const f32x4*)&ysq[il][b4 * 4];
#pragma unroll
      for (int k = 0; k < 4; ++k) acc[b4][k] = fmaf(q[k], w2, acc[b4][k]);
    }
  }
  unsigned short* wt = WT + (size_t)o * 1024 + i0;
#pragma unroll
  for (int q = 0; q < 4; ++q) *(ushort8*)(wt + q * 8) = wb[q];
  float* p = partial + (size_t)blockIdx.y * 32768 + o;
#pragma unroll
  for (int b4 = 0; b4 < 8; ++b4)
#pragma unroll
    for (int k = 0; k < 4; ++k) p[(b4 * 4 + k) * 1024] = acc[b4][k];
}

// ---------------------------------------------------------------------------
// dcalc_b (r3-verified): dmod[b,o] = rsqrt( sum_is partial[is][b][o] + eps )
// ---------------------------------------------------------------------------
__global__ __launch_bounds__(256) void dcalc_b_kernel(const float* __restrict__ partial,
                                                      float* __restrict__ dmod) {
  const int bo = blockIdx.x * 256 + threadIdx.x;
  float acc = 0.f;
#pragma unroll 8
  for (int is = 0; is < 32; ++is) acc += partial[(size_t)is * 32768 + bo];
  dmod[bo] = rsqrtf(acc + 1e-8f);
}

// ---------------------------------------------------------------------------
// Fused GEMM, 128x128 tile / 2 blocks-per-CU (co-residency fills drains):
// out[m,o] = ((Efou*ys) @ W)[m,o] * dmod[b,o].
// 256 thr (4 waves 2Mx2N, 64x64/wave), BK=64, double-buffered 32KB/buffer
// (68KB LDS total -> 2 blocks/CU at launch_bounds(256,2); VGPR cap 256).
// A: fp32 Efou -> regs -> (*ys, native bf16 cast) -> swizzled ds_write.
// B: pre-swizzled-source global_load_lds. One barrier per K-tile; the
// VM(0)+BAR drain overlaps the co-resident block's MFMA (m114 mechanism).
// Grid 2048, XCD-swizzled, bn inner -> 8 consecutive blocks share A panel.
// ---------------------------------------------------------------------------
#define NT 16      // K / BK
#define BUFSZ 32768  // per-buffer: A 16KB + B 16KB

#define BAR __builtin_amdgcn_s_barrier()
#define LGKM0 asm volatile("s_waitcnt lgkmcnt(0)" ::: "memory")
#define VM(n) asm volatile("s_waitcnt vmcnt(" #n ")" ::: "memory")
#define PRIO(x) __builtin_amdgcn_s_setprio(x)

// stage one 32-row slice (4KB) of B for K-tile t into dst buffer
#define STG_B(r, t, dst)                                                     \
  __builtin_amdgcn_global_load_lds(                                          \
      (const AS1 void*)(Ws + (size_t)(r) * 32 * 2048 + (t) * 128),           \
      (AS3 void*)((dst) + 16384 + (r) * 4096 + tid * 16), 16, 0, 0)

// issue A fp32 loads (4 rows x 8 k) + ys reads for K-tile t
#define A_ISSUE(t)                                                           \
  {                                                                          \
    const float* asrc = Efou + (size_t)(m0 + argp * 4) * 1024 + (t) * 64 + k8; \
    _Pragma("unroll") for (int rr = 0; rr < 4; ++rr) {                       \
      pa[rr][0] = *(const f32x4*)(asrc + rr * 1024);                         \
      pa[rr][1] = *(const f32x4*)(asrc + rr * 1024 + 4);                     \
    }                                                                        \
    yv[0] = *(const f32x4*)(ysS + (t) * 64 + k8);                            \
    yv[1] = *(const f32x4*)(ysS + (t) * 64 + k8 + 4);                        \
  }

// convert one row (*ys -> bf16 native cast, RNE) and swizzled ds_write
#define ACVT_ROW(dst, rr)                                                    \
  {                                                                          \
    const int row = argp * 4 + (rr);                                         \
    bf16x8 ov;                                                               \
    _Pragma("unroll") for (int q = 0; q < 4; ++q) {                          \
      ov[q] = (__bf16)(pa[rr][0][q] * yv[0][q]);                             \
      ov[q + 4] = (__bf16)(pa[rr][1][q] * yv[1][q]);                         \
    }                                                                        \
    *(bf16x8*)((dst) + row * 128 + ((kslot * 16) ^ ((row & 7) << 4))) = ov;  \
  }

// swizzled fragment reads (row&7 == l15&7 for all frags)
#define RD_A(mi, kk)                                                         \
  (*(const bf16x8*)(Ab + (wr * 64 + (mi) * 16 + l15) * 128 +                 \
                    ((((kk) * 64 + lhi * 16)) ^ swz_rd)))
#define RD_B(nf, kk)                                                         \
  (*(const bf16x8*)(Bb + (wc * 64 + (nf) * 16 + l15) * 128 +                 \
                    ((((kk) * 64 + lhi * 16)) ^ swz_rd)))

__global__ __launch_bounds__(256, 2) void gemmf7_kernel(
    const float* __restrict__ Efou, const float* __restrict__ y,
    const unsigned short* __restrict__ WT, const float* __restrict__ dmod,
    float* __restrict__ out) {
  extern __shared__ char lds[];
  float* ysS = (float*)(lds + 2 * BUFSZ);  // 4KB ys table

  const int tid = threadIdx.x;
  const int bid = blockIdx.x;                   // 0..2047
  const int wg = (bid & 7) * 256 + (bid >> 3);  // bijective XCD swizzle
  const int bm = wg >> 3, bn = wg & 7;          // bn inner: A-panel reuse
  const int m0 = bm * 128, n0 = bn * 128;
  const int b = m0 >> 10;  // 128 | 1024 -> uniform per block

  const int w = tid >> 6, l = tid & 63;
  const int wr = w >> 1, wc = w & 1;  // 2M x 2N waves, 64x64 per wave
  const int l15 = l & 15, lhi = l >> 4;
  const int swz_rd = (l15 & 7) << 4;

  // A reg-staging geometry: 4 rows x 8 k per thread (128 rows total)
  const int kslot = tid & 7;
  const int k8 = kslot * 8;
  const int argp = tid >> 3;  // 0..31 -> rows argp*4..+3

  // B staging: LDS written linearly; SOURCE column pre-swizzled (rule #21)
  const int srow = tid >> 3;  // 0..31
  const int scb = ((tid & 7) << 4) ^ ((srow & 7) << 4);
  const char* Ws = (const char*)WT + (size_t)(n0 + srow) * 2048 + scb;

  f32x4 acc[4][4] = {};
  bf16x8 a[4][2], bfr[4][2];
  f32x4 pa[4][2], yv[2];

  // ---- prologue ----
  {
    f32x4 yy = *(const f32x4*)(y + b * 1024 + tid * 4);
    ysS[4 * tid] = yy[0] * 0.03125f;
    ysS[4 * tid + 1] = yy[1] * 0.03125f;
    ysS[4 * tid + 2] = yy[2] * 0.03125f;
    ysS[4 * tid + 3] = yy[3] * 0.03125f;
  }
  __syncthreads();  // publish ysS
  {
    char* d0 = lds;
    STG_B(0, 0, d0); STG_B(1, 0, d0); STG_B(2, 0, d0); STG_B(3, 0, d0);
    A_ISSUE(0);
    ACVT_ROW(d0, 0); ACVT_ROW(d0, 1); ACVT_ROW(d0, 2); ACVT_ROW(d0, 3);
  }
  VM(0); LGKM0; BAR;

  // ---- main loop: one barrier per K-tile; co-resident block fills drain ----
  for (int t = 0; t < NT; ++t) {
    const char* Ab = lds + (t & 1) * BUFSZ;
    const char* Bb = Ab + 16384;
    char* dN = lds + ((t + 1) & 1) * BUFSZ;
    if (t < NT - 1) {
      A_ISSUE(t + 1);  // 8 fp32x4 loads (oldest in VMEM queue)
      STG_B(0, t + 1, dN); STG_B(1, t + 1, dN);
      STG_B(2, t + 1, dN); STG_B(3, t + 1, dN);
    }
    // fragment reads (compiler inserts precise lgkmcnt before MFMA)
#pragma unroll
    for (int mi = 0; mi < 4; ++mi)
#pragma unroll
      for (int kk = 0; kk < 2; ++kk) a[mi][kk] = RD_A(mi, kk);
#pragma unroll
    for (int nf = 0; nf < 4; ++nf)
#pragma unroll
      for (int kk = 0; kk < 2; ++kk) bfr[nf][kk] = RD_B(nf, kk);
    if (t < NT - 1) {
      // cvt waits pa via compiler vmcnt(4) (A loads older than 4 B stages)
      ACVT_ROW(dN, 0); ACVT_ROW(dN, 1); ACVT_ROW(dN, 2); ACVT_ROW(dN, 3);
    }
    PRIO(1);
#pragma unroll
    for (int mi = 0; mi < 4; ++mi)
#pragma unroll
      for (int nf = 0; nf < 4; ++nf)
#pragma unroll
        for (int kk = 0; kk < 2; ++kk)
          acc[mi][nf] = __builtin_amdgcn_mfma_f32_16x16x32_bf16(
              a[mi][kk], bfr[nf][kk], acc[mi][nf], 0, 0, 0);
    PRIO(0);
    if (t < NT - 1) { VM(0); }  // B stages done; drain overlapped by co-block
    LGKM0;  // my ds_reads + ds_writes complete before buffer flip
    BAR;
  }

  // ---- epilogue: C/D layout col=l&15, row=(l>>4)*4+j; scale by dmod ----
  const int col0 = n0 + wc * 64 + l15;
  float dv[4];
#pragma unroll
  for (int nf = 0; nf < 4; ++nf) dv[nf] = dmod[b * 1024 + col0 + nf * 16];
#pragma unroll
  for (int mi = 0; mi < 4; ++mi) {
#pragma unroll
    for (int j = 0; j < 4; ++j) {
      const int row = m0 + wr * 64 + mi * 16 + lhi * 4 + j;
      float* orow = out + (size_t)row * 1024 + col0;
#pragma unroll
      for (int nf = 0; nf < 4; ++nf) orow[nf * 16] = acc[mi][nf][j] * dv[nf];
    }
  }
}

// ---------------------------------------------------------------------------
extern "C" void kernel_launch(void* const* d_in, const int* in_sizes, int n_in,
                              void* d_out, int out_size, void* d_ws, size_t ws_size,
                              hipStream_t stream) {
  const float* Efou = (const float*)d_in[0];  // 32*1024*1024 fp32
  const float* y    = (const float*)d_in[1];  // 32*1024 fp32
  const float* W    = (const float*)d_in[2];  // 1024*1024 fp32
  float* out = (float*)d_out;

  unsigned short* WT = (unsigned short*)d_ws;               // 2 MB bf16
  float* dpart       = (float*)(WT + (size_t)1024 * 1024);  // 4 MB fp32
  float* dmod        = dpart + (size_t)32 * 32768;          // 128 KB fp32

  hipFuncSetAttribute((const void*)gemmf7_kernel,
                      hipFuncAttributeMaxDynamicSharedMemorySize, 69632);

  prep_kernel<<<dim3(4, 32), 256, 0, stream>>>(y, W, dpart, WT);
  dcalc_b_kernel<<<128, 256, 0, stream>>>(dpart, dmod);
  gemmf7_kernel<<<2048, 256, 69632, stream>>>(Efou, y, WT, dmod, out);
}